// Round 2
// baseline (441.731 us; speedup 1.0000x reference)
//
#include <hip/hip_runtime.h>

// ---------------------------------------------------------------------------
// AttnBlock: GroupNorm -> QKV (1x1 conv) -> 4-head attention (L=2048, hd=128)
//            -> out proj -> residual.   B=8, C=512, L=2048, G=4, NH=4.
// Storage dtype: float32 (per reference). Internal compute: bf16 MFMA with
// f32 accumulation (2% threshold permits). Intermediates in ws as bf16.
// Flash attention (no S materialization). hT/qT/kT/attnT kept transposed so
// every GEMM reads row-major [row, k] operands with k contiguous.
// ---------------------------------------------------------------------------

typedef unsigned short u16;
typedef __attribute__((ext_vector_type(8)))  short          bf16x8;  // MFMA A/B frag
typedef __attribute__((ext_vector_type(4)))  float          f32x4;   // MFMA C/D frag
typedef __attribute__((ext_vector_type(4)))  unsigned int   u32x4;   // 16B copy
typedef __attribute__((ext_vector_type(8)))  unsigned short u16x8;

#define MFMA16(a, b, c) __builtin_amdgcn_mfma_f32_16x16x32_bf16((a), (b), (c), 0, 0, 0)

__device__ __forceinline__ u16 f2bf(float f) {
    union { float f; unsigned int i; } cv;
    cv.f = f;
    unsigned int u = cv.i;
    u += 0x7fffu + ((u >> 16) & 1);   // RNE
    return (u16)(u >> 16);
}

#define BATCH 8
#define CCH   512
#define LEN   2048
#define NGRP  4
#define NHEAD 4
#define HD    128
#define GSIZE (128 * 2048)   // elements per (b, group)

// ---------------------------------------------------------------------------
// 0) Convert the four 512x512 f32 weight matrices to bf16 (once per launch).
// ---------------------------------------------------------------------------
__global__ __launch_bounds__(256) void wcvt_k(const float* __restrict__ w0,
                                              const float* __restrict__ w1,
                                              const float* __restrict__ w2,
                                              const float* __restrict__ w3,
                                              u16* __restrict__ dst) {
    const int mat = blockIdx.y;
    const float* src = (mat == 0) ? w0 : (mat == 1) ? w1 : (mat == 2) ? w2 : w3;
    const size_t base = (size_t)blockIdx.x * 2048 + (size_t)threadIdx.x * 8;
    f32x4 a = *(const f32x4*)(src + base);
    f32x4 b = *(const f32x4*)(src + base + 4);
    u16x8 o;
    for (int u = 0; u < 4; ++u) { o[u] = f2bf(a[u]); o[u + 4] = f2bf(b[u]); }
    *(u16x8*)(dst + (size_t)mat * 262144 + base) = o;
}

// ---------------------------------------------------------------------------
// 1) GroupNorm partial stats (f32 input): 256 blocks, 16 channels of one (b,g).
// ---------------------------------------------------------------------------
__global__ __launch_bounds__(256) void gn_stats_k(const float* __restrict__ x,
                                                  float* __restrict__ stats) {
    const int bid   = blockIdx.x;       // 0..255
    const int grp   = bid >> 3;         // b*4+g
    const int chunk = bid & 7;          // 16-channel slab
    const int b = grp >> 2, g = grp & 3;
    const float* base = x + ((size_t)(b * CCH + g * 128 + chunk * 16)) * LEN;

    float s = 0.f, ss = 0.f;
    for (int i = 0; i < 32; ++i) {
        int cid = threadIdx.x + i * 256;          // 0..8191 chunks of 4
        f32x4 dv = *(const f32x4*)(base + (size_t)cid * 4);
        for (int u = 0; u < 4; ++u) { s += dv[u]; ss += dv[u] * dv[u]; }
    }
    for (int m = 1; m < 64; m <<= 1) {
        s  += __shfl_xor(s,  m, 64);
        ss += __shfl_xor(ss, m, 64);
    }
    __shared__ float red[8];
    int wid = threadIdx.x >> 6, lane = threadIdx.x & 63;
    if (lane == 0) { red[wid * 2] = s; red[wid * 2 + 1] = ss; }
    __syncthreads();
    if (threadIdx.x == 0) {
        float ts  = red[0] + red[2] + red[4] + red[6];
        float tss = red[1] + red[3] + red[5] + red[7];
        atomicAdd(&stats[grp * 2],     ts);
        atomicAdd(&stats[grp * 2 + 1], tss);
    }
}

// ---------------------------------------------------------------------------
// 2) GroupNorm apply + transpose: x[b,c,l] (f32) -> hT[b,l,c] (bf16).
//    64x64 tiles through LDS.
// ---------------------------------------------------------------------------
__global__ __launch_bounds__(256) void gn_apply_k(const float* __restrict__ x,
                                                  const float* __restrict__ gns,
                                                  const float* __restrict__ gnb,
                                                  const float* __restrict__ stats,
                                                  u16* __restrict__ hT) {
    __shared__ u16 Ts[64 * 72];
    const int b = blockIdx.z, c0 = blockIdx.y * 64, l0 = blockIdx.x * 64;
    const int g = c0 >> 7;
    const int tid = threadIdx.x;

    float sum   = stats[(b * NGRP + g) * 2];
    float sumsq = stats[(b * NGRP + g) * 2 + 1];
    const float invN = 1.f / (float)GSIZE;
    float mean = sum * invN;
    float var  = sumsq * invN - mean * mean;
    float rstd = rsqrtf(var + 1e-6f);

    for (int i = 0; i < 4; ++i) {
        int cid = tid + i * 256;          // 0..1023
        int row = cid >> 4, c4 = cid & 15; // row = channel in tile, col = c4*4
        int c = c0 + row;
        float sc = gns[c] * rstd;
        float bi = gnb[c] - mean * sc;
        f32x4 dv = *(const f32x4*)(x + ((size_t)(b * CCH + c)) * LEN + l0 + c4 * 4);
        for (int u = 0; u < 4; ++u)
            Ts[row * 72 + c4 * 4 + u] = f2bf(dv[u] * sc + bi);
    }
    __syncthreads();
    for (int i = 0; i < 2; ++i) {
        int cid = tid + i * 256;          // 0..511
        int lrow = cid >> 3, c8 = cid & 7;
        u16x8 ov;
        for (int u = 0; u < 8; ++u) ov[u] = Ts[(c8 * 8 + u) * 72 + lrow];
        *(u16x8*)(hT + ((size_t)b * LEN + l0 + lrow) * CCH + c0 + c8 * 8) = ov;
    }
}

// ---------------------------------------------------------------------------
// GEMM: D[m][n] = sum_k A[m][k]*B[n][k]; operands row-major [row, 512] bf16.
// MODE 0: A=hT[b] (m=l), B=wq_bf/wk_bf (n=o, N=1024) -> qT/kT (bf16) + bias
// MODE 1: A=wv_bf (m=o), B=hT[b] (n=l) -> v[b,c,l] (bf16) + bias
// MODE 2: A=wo_bf (m=o), B=attnT[b] (n=l) -> out[b,c,l] (f32) + bias + x
// 128x128x(K=512) tiles, BK=64, 4 waves (2x2), 64 f32 acc/lane.
// ---------------------------------------------------------------------------
template <int MODE>
__global__ __launch_bounds__(256, 2) void gemm_k(const u16* __restrict__ A0,
                                                 const u16* __restrict__ B0,
                                                 const u16* __restrict__ B1,
                                                 const float* __restrict__ bias0,
                                                 const float* __restrict__ bias1,
                                                 const float* __restrict__ resid,
                                                 void* __restrict__ out0v,
                                                 u16* __restrict__ out1) {
    __shared__ u16 As[128 * 72];
    __shared__ u16 Bs[128 * 72];
    const int b  = blockIdx.z;
    const int n0 = blockIdx.x * 128;
    const int m0 = blockIdx.y * 128;
    const int tid = threadIdx.x;
    const int lane = tid & 63, wid = tid >> 6;
    const int quad = lane >> 4, l15 = lane & 15;
    const int wm = (wid & 1) * 64, wn = (wid >> 1) * 64;

    const u16* Arow;
    if constexpr (MODE == 0) Arow = A0 + ((size_t)b * LEN + m0) * 512;
    else                     Arow = A0 + (size_t)m0 * 512;

    const u16* Brow;
    int col0 = 0;
    if constexpr (MODE == 0) {
        if (n0 < 512) { Brow = B0 + (size_t)n0 * 512;         col0 = n0; }
        else          { Brow = B1 + (size_t)(n0 - 512) * 512;  col0 = n0 - 512; }
    } else {
        Brow = B0 + ((size_t)b * LEN + n0) * 512;
    }

    f32x4 acc[4][4] = {};

    for (int kk = 0; kk < 8; ++kk) {
        const int k0 = kk * 64;
        __syncthreads();
        for (int i = 0; i < 4; ++i) {
            int cid = tid + i * 256;          // 0..1023
            int row = cid >> 3, c8 = cid & 7;
            *(u32x4*)(&As[row * 72 + c8 * 8]) =
                *(const u32x4*)(Arow + (size_t)row * 512 + k0 + c8 * 8);
            *(u32x4*)(&Bs[row * 72 + c8 * 8]) =
                *(const u32x4*)(Brow + (size_t)row * 512 + k0 + c8 * 8);
        }
        __syncthreads();
        for (int ks = 0; ks < 2; ++ks) {
            bf16x8 af[4], bfr[4];
            for (int t = 0; t < 4; ++t) {
                af[t]  = *(const bf16x8*)(&As[(wm + t * 16 + l15) * 72 + ks * 32 + quad * 8]);
                bfr[t] = *(const bf16x8*)(&Bs[(wn + t * 16 + l15) * 72 + ks * 32 + quad * 8]);
            }
            for (int mt = 0; mt < 4; ++mt)
                for (int nt = 0; nt < 4; ++nt)
                    acc[mt][nt] = MFMA16(af[mt], bfr[nt], acc[mt][nt]);
        }
    }

    if constexpr (MODE == 0) {
        const float* biasp = (n0 < 512) ? (bias0 + col0) : (bias1 + col0);
        u16* outp = (n0 < 512) ? (u16*)out0v : out1;
        for (int nt = 0; nt < 4; ++nt) {
            int nl = wn + nt * 16 + l15;
            float bv_ = biasp[nl];
            for (int mt = 0; mt < 4; ++mt)
                for (int r = 0; r < 4; ++r) {
                    int ml = wm + mt * 16 + quad * 4 + r;
                    size_t idx = ((size_t)b * LEN + m0 + ml) * 512 + col0 + nl;
                    outp[idx] = f2bf(acc[mt][nt][r] + bv_);
                }
        }
    } else {
        for (int mt = 0; mt < 4; ++mt)
            for (int r = 0; r < 4; ++r) {
                int ml = wm + mt * 16 + quad * 4 + r;
                float bv_ = bias0[m0 + ml];
                for (int nt = 0; nt < 4; ++nt) {
                    int nl = wn + nt * 16 + l15;
                    size_t idx = ((size_t)(b * 512 + m0 + ml)) * LEN + n0 + nl;
                    float val = acc[mt][nt][r] + bv_;
                    if constexpr (MODE == 2) {
                        ((float*)out0v)[idx] = val + resid[idx];
                    } else {
                        ((u16*)out0v)[idx] = f2bf(val);
                    }
                }
            }
    }
}

// ---------------------------------------------------------------------------
// Flash attention. Block = (b, h, 128-query tile), 4 waves, each owns 32 rows.
// qT/kT are bf16 [B, L, 512] (head slice = cols h*128..), v is bf16 [B, C, L].
// Single 128x136 LDS buffer: stages K tile for QK^T, then (after a barrier)
// is overwritten with this block's P tile for PV. Output -> attnT[b, l, c].
// ---------------------------------------------------------------------------
__global__ __launch_bounds__(256, 2) void attn_k(const u16* __restrict__ qT,
                                                 const u16* __restrict__ kT,
                                                 const u16* __restrict__ v,
                                                 u16* __restrict__ attnT) {
    __shared__ u16 Ks[128 * 136];   // 34.8 KB; doubles as the P buffer
    const int b = blockIdx.z, h = blockIdx.y;
    const int i0 = blockIdx.x * 128;
    const int tid = threadIdx.x, lane = tid & 63, wid = tid >> 6;
    const int quad = lane >> 4, l15 = lane & 15;

    // Q fragments, register resident: A[m][k], m = own row, k = d
    bf16x8 qa[2][4];
    for (int mt = 0; mt < 2; ++mt)
        for (int ks = 0; ks < 4; ++ks) {
            int m = i0 + wid * 32 + mt * 16 + l15;
            qa[mt][ks] = *(const bf16x8*)(qT + ((size_t)b * LEN + m) * 512 + h * HD +
                                          ks * 32 + quad * 8);
        }

    float mst[2][4], lst[2][4];
    for (int mt = 0; mt < 2; ++mt)
        for (int r = 0; r < 4; ++r) { mst[mt][r] = -3.0e38f; lst[mt][r] = 0.f; }
    f32x4 oacc[2][8] = {};

    const float scale = 0.08838834764831845f;   // 128^-0.5
    const float L2E   = 1.4426950408889634f;

    for (int jt = 0; jt < 16; ++jt) {
        const int j0 = jt * 128;
        __syncthreads();   // prev iter's P reads (PV) done before restage
        for (int i = 0; i < 8; ++i) {
            int cid = tid + i * 256;           // 0..2047
            int row = cid >> 4, c8 = cid & 15;
            *(u32x4*)(&Ks[row * 136 + c8 * 8]) =
                *(const u32x4*)(kT + ((size_t)b * LEN + j0 + row) * 512 + h * HD + c8 * 8);
        }
        __syncthreads();

        // S = Q K^T for this wave's 32 rows x 128 keys
        f32x4 sacc[2][8] = {};
        for (int nt = 0; nt < 8; ++nt)
            for (int ks = 0; ks < 4; ++ks) {
                bf16x8 kf = *(const bf16x8*)(&Ks[(nt * 16 + l15) * 136 + ks * 32 + quad * 8]);
                sacc[0][nt] = MFMA16(qa[0][ks], kf, sacc[0][nt]);
                sacc[1][nt] = MFMA16(qa[1][ks], kf, sacc[1][nt]);
            }

        // online softmax (each S row lives across the 16 lanes of a quad)
        for (int mt = 0; mt < 2; ++mt)
            for (int r = 0; r < 4; ++r) {
                float rm = -3.0e38f;
                for (int nt = 0; nt < 8; ++nt) rm = fmaxf(rm, sacc[mt][nt][r]);
                rm *= scale;
                for (int msk = 1; msk < 16; msk <<= 1)
                    rm = fmaxf(rm, __shfl_xor(rm, msk, 64));
                float mnew  = fmaxf(mst[mt][r], rm);
                float alpha = __builtin_amdgcn_exp2f((mst[mt][r] - mnew) * L2E);
                mst[mt][r] = mnew;
                float rs = 0.f;
                for (int nt = 0; nt < 8; ++nt) {
                    float p = __builtin_amdgcn_exp2f((sacc[mt][nt][r] * scale - mnew) * L2E);
                    sacc[mt][nt][r] = p;
                    rs += p;
                }
                for (int msk = 1; msk < 16; msk <<= 1)
                    rs += __shfl_xor(rs, msk, 64);
                lst[mt][r] = lst[mt][r] * alpha + rs;
                for (int dt = 0; dt < 8; ++dt) oacc[mt][dt][r] *= alpha;
            }

        // All waves' QK^T reads of Ks must finish before P overwrites it.
        __syncthreads();

        // P -> LDS (same buffer). Each wave writes only its own 32 rows and
        // its PV A-frags read only those rows -> no further barrier needed.
        for (int mt = 0; mt < 2; ++mt)
            for (int nt = 0; nt < 8; ++nt)
                for (int r = 0; r < 4; ++r) {
                    int ml = wid * 32 + mt * 16 + quad * 4 + r;
                    Ks[ml * 136 + nt * 16 + l15] = f2bf(sacc[mt][nt][r]);
                }

        // PV: O[m][d] += P[m][j] * v[d][j]  (V B-frags straight from global)
        for (int ks = 0; ks < 4; ++ks) {
            bf16x8 pf0 = *(const bf16x8*)(&Ks[(wid * 32 + l15) * 136 + ks * 32 + quad * 8]);
            bf16x8 pf1 = *(const bf16x8*)(&Ks[(wid * 32 + 16 + l15) * 136 + ks * 32 + quad * 8]);
            for (int dt = 0; dt < 8; ++dt) {
                bf16x8 vf = *(const bf16x8*)(v + ((size_t)(b * CCH + h * HD + dt * 16 + l15)) * LEN +
                                             j0 + ks * 32 + quad * 8);
                oacc[0][dt] = MFMA16(pf0, vf, oacc[0][dt]);
                oacc[1][dt] = MFMA16(pf1, vf, oacc[1][dt]);
            }
        }
    }

    for (int mt = 0; mt < 2; ++mt)
        for (int r = 0; r < 4; ++r) {
            int m = i0 + wid * 32 + mt * 16 + quad * 4 + r;
            float inv = 1.f / lst[mt][r];
            for (int dt = 0; dt < 8; ++dt) {
                int d = dt * 16 + l15;
                attnT[((size_t)b * LEN + m) * 512 + h * HD + d] =
                    f2bf(oacc[mt][dt][r] * inv);
            }
        }
}

// ---------------------------------------------------------------------------
extern "C" void kernel_launch(void* const* d_in, const int* in_sizes, int n_in,
                              void* d_out, int out_size, void* d_ws, size_t ws_size,
                              hipStream_t stream) {
    const float* x   = (const float*)d_in[0];
    const float* gns = (const float*)d_in[1];
    const float* gnb = (const float*)d_in[2];
    const float* wq  = (const float*)d_in[3];
    const float* bq  = (const float*)d_in[4];
    const float* wk  = (const float*)d_in[5];
    const float* bk  = (const float*)d_in[6];
    const float* wv  = (const float*)d_in[7];
    const float* bv  = (const float*)d_in[8];
    const float* wo  = (const float*)d_in[9];
    const float* bo  = (const float*)d_in[10];
    float* out = (float*)d_out;

    const size_t NEL = (size_t)BATCH * CCH * LEN;   // 8388608
    float* stats = (float*)d_ws;                     // 64 floats @ 0
    u16* wcat  = (u16*)((char*)d_ws + 256);          // 4 x 512x512 bf16 weights
    u16* hT    = wcat + 4 * 262144;                  // bf16 [B,L,C]; reused as attnT
    u16* qT    = hT + NEL;
    u16* kT    = qT + NEL;
    u16* vbuf  = kT + NEL;
    u16* attnT = hT;   // hT dead after gemm<1>; alias to save 16 MB

    const u16* wq_bf = wcat;
    const u16* wk_bf = wcat + 262144;
    const u16* wv_bf = wcat + 2 * 262144;
    const u16* wo_bf = wcat + 3 * 262144;

    hipMemsetAsync(d_ws, 0, 256, stream);
    wcvt_k<<<dim3(128, 4), 256, 0, stream>>>(wq, wk, wv, wo, wcat);
    gn_stats_k<<<256, 256, 0, stream>>>(x, stats);
    gn_apply_k<<<dim3(32, 8, 8), 256, 0, stream>>>(x, gns, gnb, stats, hT);
    gemm_k<0><<<dim3(8, 16, 8), 256, 0, stream>>>(hT, wq_bf, wk_bf, bq, bk, nullptr, qT, kT);
    gemm_k<1><<<dim3(16, 4, 8), 256, 0, stream>>>(wv_bf, hT, nullptr, bv, nullptr, nullptr, vbuf, nullptr);
    attn_k<<<dim3(16, 4, 8), 256, 0, stream>>>(qT, kT, vbuf, attnT);
    gemm_k<2><<<dim3(16, 4, 8), 256, 0, stream>>>(wo_bf, attnT, nullptr, bo, nullptr, x, out, nullptr);
}